// Round 18
// baseline (153.446 us; speedup 1.0000x reference)
//
#include <hip/hip_runtime.h>

typedef float f32x4 __attribute__((ext_vector_type(4)));

// x: [1, 2049, 8192] f32 ; lambda: [1, 8192] f32
// out: [1, 1+2048+8192, 8192] f32
//
// R18: K1 as a LINEAR fused scale-copy + abs-reduce. Grid-stride of
// 2048x256 threads over f32x4 slots; the stride (524288 slots) is an exact
// multiple of the row length (2048 slots), so each thread owns a fixed
// 4-column slot -> single f32x4 accumulator, partials[p= g/2048][c= g%2048].
// Plain loads + plain stores (linear-stream rule, R12/K4). Fallback to the
// proven R12 col-sliced K1 if ws can't hold the 8 MB partials.

// K1-linear: fused scaled copy + per-thread abs accumulation.
__global__ __launch_bounds__(256) void k_fused_linear(
    const float* __restrict__ x, const float* __restrict__ lam,
    float* __restrict__ out, float* __restrict__ partials,
    long i0, long nIter, long strideSlots, int lamMask)
{
    const long g = (long)blockIdx.x * 256 + threadIdx.x;
    const f32x4* xv = (const f32x4*)x;
    const f32x4* lv = (const f32x4*)lam;
    f32x4*       ov = (f32x4*)out;
    const f32x4 l4 = lv[g & lamMask];
    f32x4 acc = {0.f, 0.f, 0.f, 0.f};
    long i = i0 + g;
    for (long k = 0; k < nIter; ++k, i += strideSlots) {
        const f32x4 v = xv[i];
        acc.x += fabsf(v.x); acc.y += fabsf(v.y);
        acc.z += fabsf(v.z); acc.w += fabsf(v.w);
        ov[i] = v * l4;
    }
    ((f32x4*)partials)[g] = acc;     // layout: [p][c] with g = p*(N/4)+c
}

// K1-fallback: R12's fused col-sliced kernel (NT/NT), used only if ws small.
__global__ __launch_bounds__(256) void k_errs_partial(
    const float* __restrict__ x, const float* __restrict__ lam,
    float* __restrict__ out, float* __restrict__ partials,
    int N, int rowsPerChunk)
{
    const int col = (blockIdx.x * 256 + threadIdx.x) * 4;
    const int r0  = 1 + blockIdx.y * rowsPerChunk;
    const f32x4 l4 = *(const f32x4*)(lam + col);
    f32x4 acc = {0.f, 0.f, 0.f, 0.f};
    #pragma unroll 4
    for (int r = r0; r < r0 + rowsPerChunk; ++r) {
        const f32x4 v = __builtin_nontemporal_load((const f32x4*)(x + (size_t)r * N + col));
        acc.x += fabsf(v.x); acc.y += fabsf(v.y); acc.z += fabsf(v.z); acc.w += fabsf(v.w);
        __builtin_nontemporal_store(v * l4, (f32x4*)(out + (size_t)r * N + col));
    }
    *(f32x4*)(partials + (size_t)blockIdx.y * N + col) = acc;
}

// K2: reduce partials per column, write center (out row 0), flags, vals.
__global__ __launch_bounds__(256) void k_stats(
    const float* __restrict__ x, const float* __restrict__ lam,
    const float* __restrict__ partials,
    float* __restrict__ out, float* __restrict__ vals, int* __restrict__ flags,
    int N, int P)
{
    const int n = blockIdx.x * 256 + threadIdx.x;
    float s = 0.f;
    for (int p = 0; p < P; ++p) s += partials[(size_t)p * N + n];
    const float x0 = x[n];          // row 0 of x
    const float l  = lam[n];
    const float lower = x0 - s;
    const float upper = x0 + s;
    out[n] = l * x0 - l * lower * 0.5f;          // center
    const bool has = (lower < 0.f) && (upper > 0.f);
    flags[n] = has ? 1 : 0;
    vals[n]  = has ? (-l * lower * 0.5f) : 0.f;
}

// K3: single-block scan of flags -> inverse map colOfRow[r] = column (or -1).
__global__ __launch_bounds__(256) void k_scan(
    const int* __restrict__ flags, int* __restrict__ colOfRow, int N)
{
    __shared__ int waveSums[4];
    const int t    = threadIdx.x;
    const int per  = N / 256;         // 32
    const int base = t * per;
    int f[32];
    int cnt = 0;
    #pragma unroll
    for (int i = 0; i < 32; ++i) {
        f[i] = flags[base + i];
        cnt += f[i];
        colOfRow[base + i] = -1;      // init; ordered vs scatter by barrier below
    }
    const int lane = t & 63;
    const int wid  = t >> 6;
    int v = cnt;
    #pragma unroll
    for (int off = 1; off < 64; off <<= 1) {
        const int u = __shfl_up(v, off, 64);
        if (lane >= off) v += u;
    }
    if (lane == 63) waveSums[wid] = v;
    __syncthreads();
    int wadd = 0;
    for (int w = 0; w < wid; ++w) wadd += waveSums[w];
    int run = v - cnt + wadd;         // exclusive prefix
    #pragma unroll
    for (int i = 0; i < 32; ++i) {
        if (f[i]) { colOfRow[run] = base + i; run += 1; }
    }
}

// K4: extra block, row-owned: block b fills rpb=8 contiguous rows (256 KB
// linear) injecting vals[colOfRow[r]]. Plain stores (R12: NT cost ~20%).
__global__ __launch_bounds__(256) void k_extra_rows(
    const float* __restrict__ vals, const int* __restrict__ colOfRow,
    float* __restrict__ outExtra, int N, int rowsPerBlock)
{
    const int t  = threadIdx.x;
    const int r0 = blockIdx.x * rowsPerBlock;
    for (int r = r0; r < r0 + rowsPerBlock; ++r) {
        const int   c  = colOfRow[r];             // broadcast scalar read
        const float vv = (c >= 0) ? vals[c] : 0.f;
        float* rowp = outExtra + (size_t)r * N;
        #pragma unroll
        for (int s = 0; s < 8; ++s) {
            const int col = (s * 256 + t) * 4;
            f32x4 o;
            o.x = (c == col    ) ? vv : 0.f;
            o.y = (c == col + 1) ? vv : 0.f;
            o.z = (c == col + 2) ? vv : 0.f;
            o.w = (c == col + 3) ? vv : 0.f;
            *(f32x4*)(rowp + col) = o;            // plain store
        }
    }
}

extern "C" void kernel_launch(void* const* d_in, const int* in_sizes, int n_in,
                              void* d_out, int out_size, void* d_ws, size_t ws_size,
                              hipStream_t stream) {
    const float* x   = (const float*)d_in[0];
    const float* lam = (const float*)d_in[1];
    float* out = (float*)d_out;

    const int N  = in_sizes[1];            // 8192
    const int E1 = in_sizes[0] / N;        // 2049
    const int E  = E1 - 1;                 // 2048

    float* outExtra = out + (size_t)E1 * N;
    dim3 blk(256);

    // ---- K1 selection: linear-fused if geometry + ws allow, else R12 path.
    const long slotsPerRow = N / 4;                    // 2048
    const long gridBlocks  = 2048;
    const long gridThreads = gridBlocks * 256;         // 524288
    const long totalSlots  = (long)E * slotsPerRow;    // rows 1..E
    const bool geomOK = (gridThreads % slotsPerRow) == 0 &&
                        (totalSlots % gridThreads) == 0;
    const long PB_lin = gridThreads / slotsPerRow;     // 256 partial rows
    const size_t needLin = ((size_t)PB_lin * N + 3 * (size_t)N) * 4;  // ~8.1 MB

    int PB;            // partial row count actually used
    float* partials = (float*)d_ws;
    if (geomOK && needLin <= ws_size) {
        PB = (int)PB_lin;
        const long i0 = slotsPerRow;                   // row 1
        const long nIter = totalSlots / gridThreads;   // 8
        hipLaunchKernelGGL(k_fused_linear, dim3(gridBlocks), blk, 0, stream,
                           x, lam, out, partials,
                           i0, nIter, gridThreads, (int)slotsPerRow - 1);
    } else {
        PB = 32;
        hipLaunchKernelGGL(k_errs_partial, dim3(N / 1024, PB), blk, 0, stream,
                           x, lam, out, partials, N, E / PB);
    }

    float* vals     = partials + (size_t)PB * N;       // [N]
    int*   flags    = (int*)(vals + N);                // [N]
    int*   colOfRow = flags + N;                       // [N]

    hipLaunchKernelGGL(k_stats, dim3(N / 256), blk, 0, stream,
                       x, lam, partials, out, vals, flags, N, PB);

    hipLaunchKernelGGL(k_scan, dim3(1), blk, 0, stream,
                       flags, colOfRow, N);

    const int rpb = 8;                     // 1024 blocks, 256 KB linear per block
    hipLaunchKernelGGL(k_extra_rows, dim3(N / rpb), blk, 0, stream,
                       vals, colOfRow, outExtra, N, rpb);
}

// Round 19
// 86.109 us; speedup vs baseline: 1.7820x; 1.7820x over previous
//
#include <hip/hip_runtime.h>

typedef float f32x4 __attribute__((ext_vector_type(4)));

// FINAL (R12 revert — best measured: 86.5us, absmax 0).
// x: [1, 2049, 8192] f32 ; lambda: [1, 8192] f32
// out: [1, 1+2048+8192, 8192] f32
//   row 0           : center = lam*x0 - 0.5*lam*lower
//   rows 1..2048    : x[e]*lam
//   rows 2049..10240: one value per crossing column at row cumsum(has)-1, else 0
//
// Measured rules (this session, gfx950):
//   - fused mixed r/w col-sliced stream: NT load + NT store, 256 blocks (R12)
//     * plain-store +12.6us (R13), plain-load +15.7us (R15), more blocks +22us (R7)
//     * row-owned or linear restructures: +57/+67us (R14/R18); splits +20us (R16)
//   - linear store stream (K4): plain stores; NT costs ~20% (R12 vs R5)
//   - K4 row-owned 8 rows/block (256KB linear) at 6.8 TB/s = fill ceiling

// K1: fused errs-scale + per-row-chunk abs partial sums.
// grid (8, 32) = 256 long-stream blocks, NT loads + NT stores.
__global__ __launch_bounds__(256) void k_errs_partial(
    const float* __restrict__ x, const float* __restrict__ lam,
    float* __restrict__ out, float* __restrict__ partials,
    int N, int rowsPerChunk)
{
    const int col = (blockIdx.x * 256 + threadIdx.x) * 4;
    const int r0  = 1 + blockIdx.y * rowsPerChunk;
    const f32x4 l4 = *(const f32x4*)(lam + col);
    f32x4 acc = {0.f, 0.f, 0.f, 0.f};
    #pragma unroll 4
    for (int r = r0; r < r0 + rowsPerChunk; ++r) {
        const f32x4 v = __builtin_nontemporal_load((const f32x4*)(x + (size_t)r * N + col));
        acc.x += fabsf(v.x); acc.y += fabsf(v.y); acc.z += fabsf(v.z); acc.w += fabsf(v.w);
        __builtin_nontemporal_store(v * l4, (f32x4*)(out + (size_t)r * N + col));
    }
    *(f32x4*)(partials + (size_t)blockIdx.y * N + col) = acc;
}

// K2: reduce partials per column, write center (out row 0), flags, vals.
__global__ __launch_bounds__(256) void k_stats(
    const float* __restrict__ x, const float* __restrict__ lam,
    const float* __restrict__ partials,
    float* __restrict__ out, float* __restrict__ vals, int* __restrict__ flags,
    int N, int P)
{
    const int n = blockIdx.x * 256 + threadIdx.x;
    float s = 0.f;
    for (int p = 0; p < P; ++p) s += partials[(size_t)p * N + n];
    const float x0 = x[n];          // row 0 of x
    const float l  = lam[n];
    const float lower = x0 - s;
    const float upper = x0 + s;
    out[n] = l * x0 - l * lower * 0.5f;          // center
    const bool has = (lower < 0.f) && (upper > 0.f);
    flags[n] = has ? 1 : 0;
    vals[n]  = has ? (-l * lower * 0.5f) : 0.f;
}

// K3: single-block scan of flags -> inverse map colOfRow[r] = column (or -1).
__global__ __launch_bounds__(256) void k_scan(
    const int* __restrict__ flags, int* __restrict__ colOfRow, int N)
{
    __shared__ int waveSums[4];
    const int t    = threadIdx.x;
    const int per  = N / 256;         // 32
    const int base = t * per;
    int f[32];
    int cnt = 0;
    #pragma unroll
    for (int i = 0; i < 32; ++i) {
        f[i] = flags[base + i];
        cnt += f[i];
        colOfRow[base + i] = -1;      // init; ordered vs scatter by barrier below
    }
    const int lane = t & 63;
    const int wid  = t >> 6;
    int v = cnt;
    #pragma unroll
    for (int off = 1; off < 64; off <<= 1) {
        const int u = __shfl_up(v, off, 64);
        if (lane >= off) v += u;
    }
    if (lane == 63) waveSums[wid] = v;
    __syncthreads();
    int wadd = 0;
    for (int w = 0; w < wid; ++w) wadd += waveSums[w];
    int run = v - cnt + wadd;         // exclusive prefix
    #pragma unroll
    for (int i = 0; i < 32; ++i) {
        if (f[i]) { colOfRow[run] = base + i; run += 1; }
    }
}

// K4: extra block, row-owned: block b fills rpb=8 contiguous rows (256 KB
// linear) injecting vals[colOfRow[r]]. Plain stores.
__global__ __launch_bounds__(256) void k_extra_rows(
    const float* __restrict__ vals, const int* __restrict__ colOfRow,
    float* __restrict__ outExtra, int N, int rowsPerBlock)
{
    const int t  = threadIdx.x;
    const int r0 = blockIdx.x * rowsPerBlock;
    for (int r = r0; r < r0 + rowsPerBlock; ++r) {
        const int   c  = colOfRow[r];             // broadcast scalar read
        const float vv = (c >= 0) ? vals[c] : 0.f;
        float* rowp = outExtra + (size_t)r * N;
        #pragma unroll
        for (int s = 0; s < 8; ++s) {
            const int col = (s * 256 + t) * 4;
            f32x4 o;
            o.x = (c == col    ) ? vv : 0.f;
            o.y = (c == col + 1) ? vv : 0.f;
            o.z = (c == col + 2) ? vv : 0.f;
            o.w = (c == col + 3) ? vv : 0.f;
            *(f32x4*)(rowp + col) = o;            // plain store
        }
    }
}

extern "C" void kernel_launch(void* const* d_in, const int* in_sizes, int n_in,
                              void* d_out, int out_size, void* d_ws, size_t ws_size,
                              hipStream_t stream) {
    const float* x   = (const float*)d_in[0];
    const float* lam = (const float*)d_in[1];
    float* out = (float*)d_out;

    const int N  = in_sizes[1];            // 8192
    const int E1 = in_sizes[0] / N;        // 2049
    const int E  = E1 - 1;                 // 2048

    const int PBY = 32;
    float* outExtra = out + (size_t)E1 * N;

    float* partials = (float*)d_ws;                     // [PBY][N]
    float* vals     = partials + (size_t)PBY * N;       // [N]
    int*   flags    = (int*)(vals + N);                 // [N]
    int*   colOfRow = flags + N;                        // [N]

    dim3 blk(256);

    dim3 g1(N / 1024, PBY);
    hipLaunchKernelGGL(k_errs_partial, g1, blk, 0, stream,
                       x, lam, out, partials, N, E / PBY);

    hipLaunchKernelGGL(k_stats, dim3(N / 256), blk, 0, stream,
                       x, lam, partials, out, vals, flags, N, PBY);

    hipLaunchKernelGGL(k_scan, dim3(1), blk, 0, stream,
                       flags, colOfRow, N);

    const int rpb = 8;                     // 1024 blocks, 256 KB linear per block
    hipLaunchKernelGGL(k_extra_rows, dim3(N / rpb), blk, 0, stream,
                       vals, colOfRow, outExtra, N, rpb);
}